// Round 3
// baseline (21167.409 us; speedup 1.0000x reference)
//
#include <hip/hip_runtime.h>
#include <math.h>

typedef __attribute__((ext_vector_type(8))) short short8;
typedef __attribute__((ext_vector_type(4))) float floatx4;

__device__ __forceinline__ float b2f(ushort u) {
    union { uint i; float f; } c; c.i = ((uint)u) << 16; return c.f;
}
__device__ __forceinline__ ushort f2b(float f) {
    union { float f; uint i; } c; c.f = f;
    return (ushort)((c.i + 0x7fffu + ((c.i >> 16) & 1u)) >> 16);
}

// ---------------- fp32 -> bf16 converter (weights) ----------------
__global__ __launch_bounds__(256) void cvt_kernel(
    const float* __restrict__ S, ushort* __restrict__ D, int n4)
{
    int i = blockIdx.x * 256 + threadIdx.x;
    if (i < n4) {
        float4 f = ((const float4*)S)[i];
        ushort4 o;
        o.x = f2b(f.x); o.y = f2b(f.y); o.z = f2b(f.z); o.w = f2b(f.w);
        ((ushort4*)D)[i] = o;
    }
}

// ---------------- LayerNorm: fp32 in, bf16 out; one block per row, D=1024 ----------------
__global__ __launch_bounds__(256) void ln_kernel(
    const float* __restrict__ X, const float* __restrict__ G,
    const float* __restrict__ Bb, ushort* __restrict__ Y)
{
    const int row = blockIdx.x;
    const int t = threadIdx.x;
    const float* xr = X + (size_t)row * 1024;
    float4 p = ((const float4*)xr)[t];
    float s = p.x + p.y + p.z + p.w;
    float s2 = p.x * p.x + p.y * p.y + p.z * p.z + p.w * p.w;
    #pragma unroll
    for (int off = 32; off > 0; off >>= 1) {
        s += __shfl_down(s, off);
        s2 += __shfl_down(s2, off);
    }
    __shared__ float rs1[4], rs2[4];
    if ((t & 63) == 0) { rs1[t >> 6] = s; rs2[t >> 6] = s2; }
    __syncthreads();
    float S1 = rs1[0] + rs1[1] + rs1[2] + rs1[3];
    float S2 = rs2[0] + rs2[1] + rs2[2] + rs2[3];
    float mu = S1 * (1.0f / 1024.0f);
    float var = S2 * (1.0f / 1024.0f) - mu * mu;
    float rstd = rsqrtf(var + 1e-12f);
    float4 gp = ((const float4*)G)[t];
    float4 bp = ((const float4*)Bb)[t];
    ushort4 o;
    o.x = f2b((p.x - mu) * rstd * gp.x + bp.x);
    o.y = f2b((p.y - mu) * rstd * gp.y + bp.y);
    o.z = f2b((p.z - mu) * rstd * gp.z + bp.z);
    o.w = f2b((p.w - mu) * rstd * gp.w + bp.w);
    ((ushort4*)(Y + (size_t)row * 1024))[t] = o;
}

// ---------------- GEMM: C[M,N] = A[M,K] @ B[K,N] (+bias)(+silu)(+resid)
// A,B bf16; bias/resid fp32; out bf16 or fp32. 128x128 tile, BK=32, 4 waves.
template<bool BIAS, bool SILU, bool RESID, bool OUTF32>
__global__ __launch_bounds__(256) void gemm_kernel(
    const ushort* __restrict__ A, const ushort* __restrict__ Bm,
    const float* __restrict__ bias, const float* __restrict__ resid,
    void* __restrict__ Cm, int M, int N, int K)
{
    __shared__ __align__(16) ushort lsA[128][40];   // [m][k], pad 32->40
    __shared__ __align__(16) ushort lsB[128][40];   // B^T: [n][k]

    const int t = threadIdx.x;
    const int m0 = blockIdx.y * 128;
    const int n0 = blockIdx.x * 128;
    const int w = t >> 6;
    const int lane = t & 63;
    const int wm = (w >> 1) * 64;
    const int wn = (w & 1) * 64;
    const int quad = lane >> 4;
    const int l16 = lane & 15;
    const int ko = quad * 8;

    floatx4 acc[4][4];
    #pragma unroll
    for (int i = 0; i < 4; ++i)
        #pragma unroll
        for (int j = 0; j < 4; ++j)
            acc[i][j] = (floatx4){0.f, 0.f, 0.f, 0.f};

    for (int k0 = 0; k0 < K; k0 += 32) {
        __syncthreads();
        // stage A tile 128x32 (contiguous rows)
        #pragma unroll
        for (int it = 0; it < 2; ++it) {
            int idx = it * 256 + t;
            int row = idx >> 2;
            int c8 = (idx & 3) << 3;
            *(int4*)&lsA[row][c8] =
                *(const int4*)(A + (size_t)(m0 + row) * K + k0 + c8);
        }
        // stage B tile 32x128, transposed into lsB[n][k]
        #pragma unroll
        for (int it = 0; it < 2; ++it) {
            int idx = it * 256 + t;
            int kk = idx >> 4;
            int c8 = (idx & 15) << 3;
            int4 pk = *(const int4*)(Bm + (size_t)(k0 + kk) * N + n0 + c8);
            const ushort* tp = (const ushort*)&pk;
            #pragma unroll
            for (int i = 0; i < 8; ++i) lsB[c8 + i][kk] = tp[i];
        }
        __syncthreads();
        short8 af[4], bf[4];
        #pragma unroll
        for (int i = 0; i < 4; ++i) {
            af[i] = *(const short8*)&lsA[wm + i * 16 + l16][ko];
            bf[i] = *(const short8*)&lsB[wn + i * 16 + l16][ko];
        }
        #pragma unroll
        for (int i = 0; i < 4; ++i)
            #pragma unroll
            for (int j = 0; j < 4; ++j)
                acc[i][j] = __builtin_amdgcn_mfma_f32_16x16x32_bf16(
                    af[i], bf[j], acc[i][j], 0, 0, 0);
    }

    // epilogue: C/D layout col=lane&15, row=quad*4+reg
    #pragma unroll
    for (int tn = 0; tn < 4; ++tn) {
        const int n = n0 + wn + tn * 16 + l16;
        const float bv = BIAS ? bias[n] : 0.0f;
        #pragma unroll
        for (int tm = 0; tm < 4; ++tm) {
            const int mbase = m0 + wm + tm * 16 + quad * 4;
            #pragma unroll
            for (int rr = 0; rr < 4; ++rr) {
                float v = acc[tm][tn][rr] + bv;
                if (SILU) v = v / (1.0f + __expf(-v));
                const size_t off = (size_t)(mbase + rr) * N + n;
                if (RESID) v += resid[off];
                if constexpr (OUTF32) ((float*)Cm)[off] = v;
                else                  ((ushort*)Cm)[off] = f2b(v);
            }
        }
    }
}

// ---------------- Flash attention (vector ALU), causal + pad mask ----------------
// grid (S/64, B*H); block 256 = 64 rows x 4 groups; head_dim=64, scale=1/8
__global__ __launch_bounds__(256) void attn_kernel(
    const ushort* __restrict__ Qm, const ushort* __restrict__ Km,
    const ushort* __restrict__ Vm, const int* __restrict__ amask,
    ushort* __restrict__ Om)
{
    __shared__ __align__(16) float lsQP[64][68];  // Q during staging, then P
    __shared__ __align__(16) float lsK[64][68];
    __shared__ __align__(16) float lsV[64][64];
    __shared__ float red[64][4];
    __shared__ int lsM[64];

    const int qt = blockIdx.x;
    const int bh = blockIdx.y;
    const int b = bh >> 4;
    const int h = bh & 15;
    const int t = threadIdx.x;
    const int r = t >> 2;
    const int g = t & 3;

    const int q0 = qt * 64;
    const size_t base = ((size_t)b * 2048) * 1024 + (size_t)h * 64;

    #pragma unroll
    for (int it = 0; it < 2; ++it) {
        int idx = it * 256 + t;
        int row = idx >> 3;
        int c8 = (idx & 7) << 3;
        int4 pk = *(const int4*)(Qm + base + (size_t)(q0 + row) * 1024 + c8);
        const ushort* tp = (const ushort*)&pk;
        #pragma unroll
        for (int i = 0; i < 8; ++i) lsQP[row][c8 + i] = b2f(tp[i]);
    }
    __syncthreads();
    float qv[64];
    #pragma unroll
    for (int c = 0; c < 16; ++c) {
        float4 q4 = *(const float4*)&lsQP[r][c * 4];
        qv[c * 4 + 0] = q4.x; qv[c * 4 + 1] = q4.y;
        qv[c * 4 + 2] = q4.z; qv[c * 4 + 3] = q4.w;
    }
    const int mq = amask[b * 2048 + q0 + r];

    float Oa[16];
    #pragma unroll
    for (int i = 0; i < 16; ++i) Oa[i] = 0.f;
    float m_i = -INFINITY, l_i = 0.f;

    for (int kt = 0; kt <= qt; ++kt) {
        const int k0 = kt * 64;
        __syncthreads();
        #pragma unroll
        for (int it = 0; it < 2; ++it) {
            int idx = it * 256 + t;
            int row = idx >> 3;
            int c8 = (idx & 7) << 3;
            const size_t goff = base + (size_t)(k0 + row) * 1024 + c8;
            int4 pk = *(const int4*)(Km + goff);
            int4 pv = *(const int4*)(Vm + goff);
            const ushort* tk = (const ushort*)&pk;
            const ushort* tv = (const ushort*)&pv;
            #pragma unroll
            for (int i = 0; i < 8; ++i) {
                lsK[row][c8 + i] = b2f(tk[i]);
                lsV[row][c8 + i] = b2f(tv[i]);
            }
        }
        if (t < 64) lsM[t] = amask[b * 2048 + k0 + t];
        __syncthreads();

        float s[16];
        float mx = -INFINITY;
        #pragma unroll
        for (int kk = 0; kk < 16; ++kk) {
            const int kl = g * 16 + kk;
            float a = 0.f;
            #pragma unroll
            for (int c = 0; c < 16; ++c) {
                float4 k4 = *(const float4*)&lsK[kl][c * 4];
                a += qv[c * 4 + 0] * k4.x + qv[c * 4 + 1] * k4.y +
                     qv[c * 4 + 2] * k4.z + qv[c * 4 + 3] * k4.w;
            }
            const bool valid = (k0 + kl <= q0 + r) && (lsM[kl] == 1) && (mq == 1);
            s[kk] = valid ? a * 0.125f : -INFINITY;
            mx = fmaxf(mx, s[kk]);
        }
        red[r][g] = mx;
        __syncthreads();
        const float m_new = fmaxf(fmaxf(fmaxf(red[r][0], red[r][1]),
                                        fmaxf(red[r][2], red[r][3])), m_i);
        float ps = 0.f;
        #pragma unroll
        for (int kk = 0; kk < 16; ++kk) {
            float p = __expf(s[kk] - m_new);
            lsQP[r][g * 16 + kk] = p;
            ps += p;
        }
        __syncthreads();
        red[r][g] = ps;
        __syncthreads();
        const float lt = red[r][0] + red[r][1] + red[r][2] + red[r][3];
        const float alpha = (m_i == -INFINITY) ? 0.f : __expf(m_i - m_new);
        l_i = l_i * alpha + lt;
        m_i = m_new;
        #pragma unroll
        for (int i = 0; i < 16; ++i) Oa[i] *= alpha;
        #pragma unroll
        for (int c = 0; c < 16; ++c) {
            float4 p4 = *(const float4*)&lsQP[r][c * 4];
            #pragma unroll
            for (int j = 0; j < 4; ++j) {
                const float p = (j == 0) ? p4.x : (j == 1) ? p4.y : (j == 2) ? p4.z : p4.w;
                const float4* vr = (const float4*)&lsV[c * 4 + j][g * 16];
                float4 v0 = vr[0], v1 = vr[1], v2 = vr[2], v3 = vr[3];
                Oa[0]  += p * v0.x; Oa[1]  += p * v0.y; Oa[2]  += p * v0.z; Oa[3]  += p * v0.w;
                Oa[4]  += p * v1.x; Oa[5]  += p * v1.y; Oa[6]  += p * v1.z; Oa[7]  += p * v1.w;
                Oa[8]  += p * v2.x; Oa[9]  += p * v2.y; Oa[10] += p * v2.z; Oa[11] += p * v2.w;
                Oa[12] += p * v3.x; Oa[13] += p * v3.y; Oa[14] += p * v3.z; Oa[15] += p * v3.w;
            }
        }
    }

    const float inv = 1.0f / l_i;
    __align__(16) ushort ov[16];
    #pragma unroll
    for (int i = 0; i < 16; ++i) ov[i] = f2b(Oa[i] * inv);
    ushort* op = Om + base + (size_t)(q0 + r) * 1024 + g * 16;
    *(int4*)op = *(const int4*)ov;
    *(int4*)(op + 8) = *(const int4*)(ov + 8);
}

// ---------------- driver ----------------
// Inputs fp32, output fp32. Weights converted to bf16 in ws; x2 (Wo-out +
// resid) lives in d_out as fp32 and is overwritten in place by FFN2
// (read-before-write per thread). Workspace peak: 72 MiB.
extern "C" void kernel_launch(void* const* d_in, const int* in_sizes, int n_in,
                              void* d_out, int out_size, void* d_ws, size_t ws_size,
                              hipStream_t stream) {
    const float* hidden = (const float*)d_in[0];
    const int*   amask  = (const int*)d_in[1];
    const float* Wq  = (const float*)d_in[2];
    const float* Wk  = (const float*)d_in[3];
    const float* Wv  = (const float*)d_in[4];
    const float* Wo  = (const float*)d_in[5];
    const float* l1g = (const float*)d_in[6];
    const float* l1b = (const float*)d_in[7];
    const float* W1  = (const float*)d_in[8];
    const float* b1  = (const float*)d_in[9];
    const float* W2  = (const float*)d_in[10];
    const float* b2  = (const float*)d_in[11];
    const float* l2g = (const float*)d_in[12];
    const float* l2b = (const float*)d_in[13];

    const int M = 8192;
    const size_t MB = 1048576;
    char* ws = (char*)d_ws;
    ushort* xa  = (ushort*)(ws);            // [0,16): LN1 out / attn ctx / (unused later)
    ushort* qb  = (ushort*)(ws + 16 * MB);  // [16,32): q / later W1b+W2b
    ushort* kb  = (ushort*)(ws + 32 * MB);  // [32,48): k / later y (LN2 out)
    ushort* vb  = (ushort*)(ws + 48 * MB);  // [48,64): v / later FFN hb chunk
    ushort* Wqb = (ushort*)(ws + 64 * MB);  // [64,72): 4 x 2MB bf16 weights
    ushort* Wkb = Wqb + 1048576;
    ushort* Wvb = Wkb + 1048576;
    ushort* Wob = Wvb + 1048576;
    ushort* W1b = qb;                        // 8 MB
    ushort* W2b = qb + 4 * 1048576;          // 8 MB
    ushort* yb  = kb;
    ushort* hbc = vb;
    float*  x2  = (float*)d_out;

    // convert attention weights fp32 -> bf16
    cvt_kernel<<<1024, 256, 0, stream>>>(Wq, Wqb, 262144);
    cvt_kernel<<<1024, 256, 0, stream>>>(Wk, Wkb, 262144);
    cvt_kernel<<<1024, 256, 0, stream>>>(Wv, Wvb, 262144);
    cvt_kernel<<<1024, 256, 0, stream>>>(Wo, Wob, 262144);

    ln_kernel<<<M, 256, 0, stream>>>(hidden, l1g, l1b, xa);
    gemm_kernel<false, false, false, false><<<dim3(8, 64), 256, 0, stream>>>(xa, Wqb, nullptr, nullptr, qb, M, 1024, 1024);
    gemm_kernel<false, false, false, false><<<dim3(8, 64), 256, 0, stream>>>(xa, Wkb, nullptr, nullptr, kb, M, 1024, 1024);
    gemm_kernel<false, false, false, false><<<dim3(8, 64), 256, 0, stream>>>(xa, Wvb, nullptr, nullptr, vb, M, 1024, 1024);
    attn_kernel<<<dim3(32, 64), 256, 0, stream>>>(qb, kb, vb, amask, xa);
    // x2 = ctx @ Wo + hidden  -> fp32 into d_out
    gemm_kernel<false, false, true, true><<<dim3(8, 64), 256, 0, stream>>>(xa, Wob, nullptr, hidden, x2, M, 1024, 1024);

    // convert FFN weights into the (now dead) q region
    cvt_kernel<<<4096, 256, 0, stream>>>(W1, W1b, 1048576);
    cvt_kernel<<<4096, 256, 0, stream>>>(W2, W2b, 1048576);

    ln_kernel<<<M, 256, 0, stream>>>(x2, l2g, l2b, yb);
    // FFN in 4 M-chunks of 2048 rows; hb chunk (2048x4096 bf16 = 16 MiB) in vb
    for (int mc = 0; mc < 4; ++mc) {
        const size_t off = (size_t)mc * 2048 * 1024;
        gemm_kernel<true, true, false, false><<<dim3(32, 16), 256, 0, stream>>>(yb + off, W1b, b1, nullptr, hbc, 2048, 4096, 1024);
        gemm_kernel<true, false, true, true><<<dim3(8, 16), 256, 0, stream>>>(hbc, W2b, b2, x2 + off, (void*)(x2 + off), 2048, 1024, 4096);
    }
}

// Round 4
// 1854.710 us; speedup vs baseline: 11.4128x; 11.4128x over previous
//
#include <hip/hip_runtime.h>
#include <math.h>

typedef __attribute__((ext_vector_type(8))) short short8;
typedef __attribute__((ext_vector_type(4))) float floatx4;

__device__ __forceinline__ float b2f(ushort u) {
    union { uint i; float f; } c; c.i = ((uint)u) << 16; return c.f;
}
__device__ __forceinline__ ushort f2b(float f) {
    union { float f; uint i; } c; c.f = f;
    return (ushort)((c.i + 0x7fffu + ((c.i >> 16) & 1u)) >> 16);
}

// ---------------- fp32 -> bf16 converter (weights) ----------------
__global__ __launch_bounds__(256) void cvt_kernel(
    const float* __restrict__ S, ushort* __restrict__ D, int n4)
{
    int i = blockIdx.x * 256 + threadIdx.x;
    if (i < n4) {
        float4 f = ((const float4*)S)[i];
        ushort4 o;
        o.x = f2b(f.x); o.y = f2b(f.y); o.z = f2b(f.z); o.w = f2b(f.w);
        ((ushort4*)D)[i] = o;
    }
}

// ---------------- LayerNorm: fp32 in, bf16 out; one block per row, D=1024 ----------------
__global__ __launch_bounds__(256) void ln_kernel(
    const float* __restrict__ X, const float* __restrict__ G,
    const float* __restrict__ Bb, ushort* __restrict__ Y)
{
    const int row = blockIdx.x;
    const int t = threadIdx.x;
    const float* xr = X + (size_t)row * 1024;
    float4 p = ((const float4*)xr)[t];
    float s = p.x + p.y + p.z + p.w;
    float s2 = p.x * p.x + p.y * p.y + p.z * p.z + p.w * p.w;
    #pragma unroll
    for (int off = 32; off > 0; off >>= 1) {
        s += __shfl_down(s, off);
        s2 += __shfl_down(s2, off);
    }
    __shared__ float rs1[4], rs2[4];
    if ((t & 63) == 0) { rs1[t >> 6] = s; rs2[t >> 6] = s2; }
    __syncthreads();
    float S1 = rs1[0] + rs1[1] + rs1[2] + rs1[3];
    float S2 = rs2[0] + rs2[1] + rs2[2] + rs2[3];
    float mu = S1 * (1.0f / 1024.0f);
    float var = S2 * (1.0f / 1024.0f) - mu * mu;
    float rstd = rsqrtf(var + 1e-12f);
    float4 gp = ((const float4*)G)[t];
    float4 bp = ((const float4*)Bb)[t];
    ushort4 o;
    o.x = f2b((p.x - mu) * rstd * gp.x + bp.x);
    o.y = f2b((p.y - mu) * rstd * gp.y + bp.y);
    o.z = f2b((p.z - mu) * rstd * gp.z + bp.z);
    o.w = f2b((p.w - mu) * rstd * gp.w + bp.w);
    ((ushort4*)(Y + (size_t)row * 1024))[t] = o;
}

// ---------------- GEMM: C[M,N] = A[M,K] @ B[K,N] (+bias)(+silu)(+resid)
template<bool BIAS, bool SILU, bool RESID, bool OUTF32>
__global__ __launch_bounds__(256) void gemm_kernel(
    const ushort* __restrict__ A, const ushort* __restrict__ Bm,
    const float* __restrict__ bias, const float* __restrict__ resid,
    void* __restrict__ Cm, int M, int N, int K)
{
    __shared__ __align__(16) ushort lsA[128][40];
    __shared__ __align__(16) ushort lsB[128][40];

    const int t = threadIdx.x;
    const int m0 = blockIdx.y * 128;
    const int n0 = blockIdx.x * 128;
    const int w = t >> 6;
    const int lane = t & 63;
    const int wm = (w >> 1) * 64;
    const int wn = (w & 1) * 64;
    const int quad = lane >> 4;
    const int l16 = lane & 15;
    const int ko = quad * 8;

    floatx4 acc[4][4];
    #pragma unroll
    for (int i = 0; i < 4; ++i)
        #pragma unroll
        for (int j = 0; j < 4; ++j)
            acc[i][j] = (floatx4){0.f, 0.f, 0.f, 0.f};

    for (int k0 = 0; k0 < K; k0 += 32) {
        __syncthreads();
        #pragma unroll
        for (int it = 0; it < 2; ++it) {
            int idx = it * 256 + t;
            int row = idx >> 2;
            int c8 = (idx & 3) << 3;
            *(int4*)&lsA[row][c8] =
                *(const int4*)(A + (size_t)(m0 + row) * K + k0 + c8);
        }
        #pragma unroll
        for (int it = 0; it < 2; ++it) {
            int idx = it * 256 + t;
            int kk = idx >> 4;
            int c8 = (idx & 15) << 3;
            int4 pk = *(const int4*)(Bm + (size_t)(k0 + kk) * N + n0 + c8);
            const ushort* tp = (const ushort*)&pk;
            #pragma unroll
            for (int i = 0; i < 8; ++i) lsB[c8 + i][kk] = tp[i];
        }
        __syncthreads();
        short8 af[4], bf[4];
        #pragma unroll
        for (int i = 0; i < 4; ++i) {
            af[i] = *(const short8*)&lsA[wm + i * 16 + l16][ko];
            bf[i] = *(const short8*)&lsB[wn + i * 16 + l16][ko];
        }
        #pragma unroll
        for (int i = 0; i < 4; ++i)
            #pragma unroll
            for (int j = 0; j < 4; ++j)
                acc[i][j] = __builtin_amdgcn_mfma_f32_16x16x32_bf16(
                    af[i], bf[j], acc[i][j], 0, 0, 0);
    }

    #pragma unroll
    for (int tn = 0; tn < 4; ++tn) {
        const int n = n0 + wn + tn * 16 + l16;
        const float bv = BIAS ? bias[n] : 0.0f;
        #pragma unroll
        for (int tm = 0; tm < 4; ++tm) {
            const int mbase = m0 + wm + tm * 16 + quad * 4;
            #pragma unroll
            for (int rr = 0; rr < 4; ++rr) {
                float v = acc[tm][tn][rr] + bv;
                if (SILU) v = v / (1.0f + __expf(-v));
                const size_t off = (size_t)(mbase + rr) * N + n;
                if (RESID) v += resid[off];
                if constexpr (OUTF32) ((float*)Cm)[off] = v;
                else                  ((ushort*)Cm)[off] = f2b(v);
            }
        }
    }
}

// ---------------- MFMA flash attention ----------------
// grid (S/64, B*H), block 256 (4 waves). Wave w owns queries [qtile + w*16, +16).
// 16x16x32 bf16 MFMA; online softmax via 16-lane shfl_xor reductions; P goes
// C-layout -> LDS(bf16) -> A-layout within the wave (no barrier needed).
// All LDS rows padded to 72 ushorts (144 B): frag ds_read_b128 is 2-way = free.
__global__ __launch_bounds__(256) void attn_kernel(
    const ushort* __restrict__ Qm, const ushort* __restrict__ Km,
    const ushort* __restrict__ Vm, const int* __restrict__ amask,
    ushort* __restrict__ Om)
{
    __shared__ __align__(16) ushort lsQ[64][72];
    __shared__ __align__(16) ushort lsK[64][72];
    __shared__ __align__(16) ushort lsVt[64][72];  // [dim][key]
    __shared__ __align__(16) ushort lsP[64][72];   // wave-private 16-row strips
    __shared__ int lsMk[64];

    const int qt = blockIdx.x;
    const int bh = blockIdx.y;
    const int b = bh >> 4;
    const int h = bh & 15;
    const int t = threadIdx.x;
    const int w = t >> 6;
    const int lane = t & 63;
    const int quad = lane >> 4;
    const int l16 = lane & 15;

    const int q0 = qt * 64;
    const size_t base = ((size_t)b * 2048) * 1024 + (size_t)h * 64;

    // stage Q tile (64 rows x 64 cols bf16)
    #pragma unroll
    for (int it = 0; it < 2; ++it) {
        int idx = it * 256 + t;
        int row = idx >> 3;
        int c8 = (idx & 7) << 3;
        *(int4*)&lsQ[row][c8] =
            *(const int4*)(Qm + base + (size_t)(q0 + row) * 1024 + c8);
    }
    __syncthreads();

    // per-wave loop-invariant Q A-frags (m = l16, k = kstep*32 + quad*8 + j)
    short8 aq0 = *(const short8*)&lsQ[w * 16 + l16][quad * 8];
    short8 aq1 = *(const short8*)&lsQ[w * 16 + l16][32 + quad * 8];

    floatx4 Oacc[4];
    #pragma unroll
    for (int d = 0; d < 4; ++d) Oacc[d] = (floatx4){0.f, 0.f, 0.f, 0.f};
    float m_i[4] = {-INFINITY, -INFINITY, -INFINITY, -INFINITY};
    float l_i[4] = {0.f, 0.f, 0.f, 0.f};

    const int vp = t & 31;         // key-pair index for V staging
    const int vc8 = (t >> 5) << 3; // dim group for V staging

    for (int kt = 0; kt <= qt; ++kt) {
        const int k0 = kt * 64;
        __syncthreads();  // previous tile's lsK/lsVt reads complete
        // stage K tile natural [key][dim]
        #pragma unroll
        for (int it = 0; it < 2; ++it) {
            int idx = it * 256 + t;
            int row = idx >> 3;
            int c8 = (idx & 7) << 3;
            *(int4*)&lsK[row][c8] =
                *(const int4*)(Km + base + (size_t)(k0 + row) * 1024 + c8);
        }
        // stage V transposed [dim][key], key-pair packed b32 writes
        {
            int4 v0 = *(const int4*)(Vm + base + (size_t)(k0 + 2 * vp) * 1024 + vc8);
            int4 v1 = *(const int4*)(Vm + base + (size_t)(k0 + 2 * vp + 1) * 1024 + vc8);
            const ushort* p0 = (const ushort*)&v0;
            const ushort* p1 = (const ushort*)&v1;
            #pragma unroll
            for (int i = 0; i < 8; ++i) {
                uint pk = (uint)p0[i] | ((uint)p1[i] << 16);
                *(uint*)&lsVt[vc8 + i][2 * vp] = pk;
            }
        }
        if (t < 64) lsMk[t] = amask[b * 2048 + k0 + t];
        __syncthreads();

        // ---- QK^T: S[16x64] per wave ----
        floatx4 sa[4];
        #pragma unroll
        for (int j = 0; j < 4; ++j) {
            short8 bk0 = *(const short8*)&lsK[j * 16 + l16][quad * 8];
            short8 bk1 = *(const short8*)&lsK[j * 16 + l16][32 + quad * 8];
            floatx4 z = (floatx4){0.f, 0.f, 0.f, 0.f};
            z = __builtin_amdgcn_mfma_f32_16x16x32_bf16(aq0, bk0, z, 0, 0, 0);
            sa[j] = __builtin_amdgcn_mfma_f32_16x16x32_bf16(aq1, bk1, z, 0, 0, 0);
        }

        const int mj0 = lsMk[l16];
        const int mj1 = lsMk[16 + l16];
        const int mj2 = lsMk[32 + l16];
        const int mj3 = lsMk[48 + l16];
        const bool diag = (kt == qt);

        float alpha[4];
        float pvv[4][4];  // [j][rr]
        #pragma unroll
        for (int rr = 0; rr < 4; ++rr) {
            const int qrow = w * 16 + quad * 4 + rr;  // query within 64-tile
            float sv[4];
            float mxv = -INFINITY;
            #pragma unroll
            for (int j = 0; j < 4; ++j) {
                const int mjv = (j == 0) ? mj0 : (j == 1) ? mj1 : (j == 2) ? mj2 : mj3;
                float vv = sa[j][rr] * 0.125f;
                const bool valid = (mjv == 1) && (!diag || (j * 16 + l16 <= qrow));
                sv[j] = valid ? vv : -INFINITY;
                mxv = fmaxf(mxv, sv[j]);
            }
            mxv = fmaxf(mxv, __shfl_xor(mxv, 1));
            mxv = fmaxf(mxv, __shfl_xor(mxv, 2));
            mxv = fmaxf(mxv, __shfl_xor(mxv, 4));
            mxv = fmaxf(mxv, __shfl_xor(mxv, 8));
            const float m_new = fmaxf(m_i[rr], mxv);
            const float al = __expf(m_i[rr] - m_new);  // exp(-inf)=0 safe
            float ps = 0.f;
            #pragma unroll
            for (int j = 0; j < 4; ++j) {
                float p = __expf(sv[j] - m_new);
                pvv[j][rr] = p;
                ps += p;
            }
            ps += __shfl_xor(ps, 1);
            ps += __shfl_xor(ps, 2);
            ps += __shfl_xor(ps, 4);
            ps += __shfl_xor(ps, 8);
            l_i[rr] = l_i[rr] * al + ps;
            m_i[rr] = m_new;
            alpha[rr] = al;
        }

        // rescale O
        #pragma unroll
        for (int d = 0; d < 4; ++d)
            #pragma unroll
            for (int rr = 0; rr < 4; ++rr)
                Oacc[d][rr] *= alpha[rr];

        // write P (C layout) to wave-private LDS strip as bf16
        #pragma unroll
        for (int j = 0; j < 4; ++j)
            #pragma unroll
            for (int rr = 0; rr < 4; ++rr)
                lsP[w * 16 + quad * 4 + rr][j * 16 + l16] = f2b(pvv[j][rr]);

        // ---- PV: O += P @ V ----
        short8 ap0 = *(const short8*)&lsP[w * 16 + l16][quad * 8];
        short8 ap1 = *(const short8*)&lsP[w * 16 + l16][32 + quad * 8];
        #pragma unroll
        for (int d = 0; d < 4; ++d) {
            short8 bv0 = *(const short8*)&lsVt[d * 16 + l16][quad * 8];
            short8 bv1 = *(const short8*)&lsVt[d * 16 + l16][32 + quad * 8];
            Oacc[d] = __builtin_amdgcn_mfma_f32_16x16x32_bf16(ap0, bv0, Oacc[d], 0, 0, 0);
            Oacc[d] = __builtin_amdgcn_mfma_f32_16x16x32_bf16(ap1, bv1, Oacc[d], 0, 0, 0);
        }
    }

    // epilogue: normalize and store (C layout rows)
    float inv[4];
    #pragma unroll
    for (int rr = 0; rr < 4; ++rr) inv[rr] = 1.0f / l_i[rr];
    #pragma unroll
    for (int rr = 0; rr < 4; ++rr) {
        const int row = q0 + w * 16 + quad * 4 + rr;
        ushort* op = Om + base + (size_t)row * 1024;
        #pragma unroll
        for (int d = 0; d < 4; ++d)
            op[d * 16 + l16] = f2b(Oacc[d][rr] * inv[rr]);
    }
}

// ---------------- driver ----------------
extern "C" void kernel_launch(void* const* d_in, const int* in_sizes, int n_in,
                              void* d_out, int out_size, void* d_ws, size_t ws_size,
                              hipStream_t stream) {
    const float* hidden = (const float*)d_in[0];
    const int*   amask  = (const int*)d_in[1];
    const float* Wq  = (const float*)d_in[2];
    const float* Wk  = (const float*)d_in[3];
    const float* Wv  = (const float*)d_in[4];
    const float* Wo  = (const float*)d_in[5];
    const float* l1g = (const float*)d_in[6];
    const float* l1b = (const float*)d_in[7];
    const float* W1  = (const float*)d_in[8];
    const float* b1  = (const float*)d_in[9];
    const float* W2  = (const float*)d_in[10];
    const float* b2  = (const float*)d_in[11];
    const float* l2g = (const float*)d_in[12];
    const float* l2b = (const float*)d_in[13];

    const int M = 8192;
    const size_t MB = 1048576;
    char* ws = (char*)d_ws;
    ushort* xa  = (ushort*)(ws);            // [0,16): LN1 out / attn ctx
    ushort* qb  = (ushort*)(ws + 16 * MB);  // [16,32): q / later W1b+W2b
    ushort* kb  = (ushort*)(ws + 32 * MB);  // [32,48): k / later y (LN2 out)
    ushort* vb  = (ushort*)(ws + 48 * MB);  // [48,64): v / later FFN hb chunk
    ushort* Wqb = (ushort*)(ws + 64 * MB);  // [64,72): 4 x 2MB bf16 weights
    ushort* Wkb = Wqb + 1048576;
    ushort* Wvb = Wkb + 1048576;
    ushort* Wob = Wvb + 1048576;
    ushort* W1b = qb;
    ushort* W2b = qb + 4 * 1048576;
    ushort* yb  = kb;
    ushort* hbc = vb;
    float*  x2  = (float*)d_out;

    cvt_kernel<<<1024, 256, 0, stream>>>(Wq, Wqb, 262144);
    cvt_kernel<<<1024, 256, 0, stream>>>(Wk, Wkb, 262144);
    cvt_kernel<<<1024, 256, 0, stream>>>(Wv, Wvb, 262144);
    cvt_kernel<<<1024, 256, 0, stream>>>(Wo, Wob, 262144);

    ln_kernel<<<M, 256, 0, stream>>>(hidden, l1g, l1b, xa);
    gemm_kernel<false, false, false, false><<<dim3(8, 64), 256, 0, stream>>>(xa, Wqb, nullptr, nullptr, qb, M, 1024, 1024);
    gemm_kernel<false, false, false, false><<<dim3(8, 64), 256, 0, stream>>>(xa, Wkb, nullptr, nullptr, kb, M, 1024, 1024);
    gemm_kernel<false, false, false, false><<<dim3(8, 64), 256, 0, stream>>>(xa, Wvb, nullptr, nullptr, vb, M, 1024, 1024);
    attn_kernel<<<dim3(32, 64), 256, 0, stream>>>(qb, kb, vb, amask, xa);
    gemm_kernel<false, false, true, true><<<dim3(8, 64), 256, 0, stream>>>(xa, Wob, nullptr, hidden, x2, M, 1024, 1024);

    cvt_kernel<<<4096, 256, 0, stream>>>(W1, W1b, 1048576);
    cvt_kernel<<<4096, 256, 0, stream>>>(W2, W2b, 1048576);

    ln_kernel<<<M, 256, 0, stream>>>(x2, l2g, l2b, yb);
    for (int mc = 0; mc < 4; ++mc) {
        const size_t off = (size_t)mc * 2048 * 1024;
        gemm_kernel<true, true, false, false><<<dim3(32, 16), 256, 0, stream>>>(yb + off, W1b, b1, nullptr, hbc, 2048, 4096, 1024);
        gemm_kernel<true, false, true, true><<<dim3(8, 16), 256, 0, stream>>>(hbc, W2b, b2, x2 + off, (void*)(x2 + off), 2048, 1024, 4096);
    }
}

// Round 5
// 789.404 us; speedup vs baseline: 26.8144x; 2.3495x over previous
//
#include <hip/hip_runtime.h>
#include <math.h>

typedef __attribute__((ext_vector_type(8))) short short8;
typedef __attribute__((ext_vector_type(4))) float floatx4;

__device__ __forceinline__ float b2f(ushort u) {
    union { uint i; float f; } c; c.i = ((uint)u) << 16; return c.f;
}
__device__ __forceinline__ ushort f2b(float f) {
    union { float f; uint i; } c; c.f = f;
    return (ushort)((c.i + 0x7fffu + ((c.i >> 16) & 1u)) >> 16);
}

__device__ __forceinline__ void async_cp16(const ushort* g, ushort* l) {
    __builtin_amdgcn_global_load_lds(
        (const __attribute__((address_space(1))) void*)g,
        (__attribute__((address_space(3))) void*)l, 16, 0, 0);
}

// ---------------- fp32 [K,N] -> bf16 transposed [N,K] ----------------
__global__ __launch_bounds__(256) void cvt_t_kernel(
    const float* __restrict__ S, ushort* __restrict__ D, int K, int N)
{
    __shared__ float ls[32][33];
    const int k0 = blockIdx.y * 32, n0 = blockIdx.x * 32;
    const int t = threadIdx.x;
    const int kr = t >> 3, nc = (t & 7) * 4;
    float4 f = *(const float4*)(S + (size_t)(k0 + kr) * N + n0 + nc);
    ls[kr][nc] = f.x; ls[kr][nc + 1] = f.y; ls[kr][nc + 2] = f.z; ls[kr][nc + 3] = f.w;
    __syncthreads();
    const int nr = t >> 3, kc = (t & 7) * 4;
    ushort4 o;
    o.x = f2b(ls[kc][nr]); o.y = f2b(ls[kc + 1][nr]);
    o.z = f2b(ls[kc + 2][nr]); o.w = f2b(ls[kc + 3][nr]);
    *(ushort4*)(D + (size_t)(n0 + nr) * K + k0 + kc) = o;
}

// ---------------- LayerNorm: fp32 in, bf16 out; one block per row, D=1024 ----------------
__global__ __launch_bounds__(256) void ln_kernel(
    const float* __restrict__ X, const float* __restrict__ G,
    const float* __restrict__ Bb, ushort* __restrict__ Y)
{
    const int row = blockIdx.x;
    const int t = threadIdx.x;
    const float* xr = X + (size_t)row * 1024;
    float4 p = ((const float4*)xr)[t];
    float s = p.x + p.y + p.z + p.w;
    float s2 = p.x * p.x + p.y * p.y + p.z * p.z + p.w * p.w;
    #pragma unroll
    for (int off = 32; off > 0; off >>= 1) {
        s += __shfl_down(s, off);
        s2 += __shfl_down(s2, off);
    }
    __shared__ float rs1[4], rs2[4];
    if ((t & 63) == 0) { rs1[t >> 6] = s; rs2[t >> 6] = s2; }
    __syncthreads();
    float S1 = rs1[0] + rs1[1] + rs1[2] + rs1[3];
    float S2 = rs2[0] + rs2[1] + rs2[2] + rs2[3];
    float mu = S1 * (1.0f / 1024.0f);
    float var = S2 * (1.0f / 1024.0f) - mu * mu;
    float rstd = rsqrtf(var + 1e-12f);
    float4 gp = ((const float4*)G)[t];
    float4 bp = ((const float4*)Bb)[t];
    ushort4 o;
    o.x = f2b((p.x - mu) * rstd * gp.x + bp.x);
    o.y = f2b((p.y - mu) * rstd * gp.y + bp.y);
    o.z = f2b((p.z - mu) * rstd * gp.z + bp.z);
    o.w = f2b((p.w - mu) * rstd * gp.w + bp.w);
    ((ushort4*)(Y + (size_t)row * 1024))[t] = o;
}

// ---------------- GEMM (B^T form, m97 structure): C[M,N] = A[M,K] @ Bt[N,K]^T
// 128x128 tile, BK=32, 4 waves, global_load_lds width-16 staging, unpadded LDS.
template<bool BIAS, bool SILU, bool RESID, bool OUTF32>
__global__ __launch_bounds__(256) void gemm_bt_kernel(
    const ushort* __restrict__ A, const ushort* __restrict__ Bt,
    const float* __restrict__ bias, const float* __restrict__ resid,
    void* __restrict__ Cm, int M, int N, int K)
{
    __shared__ __align__(16) ushort lsA[128 * 32];
    __shared__ __align__(16) ushort lsB[128 * 32];

    const int t = threadIdx.x;
    const int m0 = blockIdx.y * 128;
    const int n0 = blockIdx.x * 128;
    const int w = t >> 6;
    const int lane = t & 63;
    const int wm = (w >> 1) * 64;
    const int wn = (w & 1) * 64;
    const int quad = lane >> 4;
    const int l16 = lane & 15;
    const int ko = quad * 8;

    // staging: wave w covers tile rows [w*32, w*32+32), 2 issues x 16 rows.
    // HW semantics: LDS dest = wave-uniform base + lane*16B (contiguous).
    const int srow = w * 32 + (lane >> 2);
    const int scol = (lane & 3) * 8;
    const ushort* gA = A + (size_t)(m0 + srow) * K + scol;
    const ushort* gB = Bt + (size_t)(n0 + srow) * K + scol;
    ushort* lA0 = &lsA[(w * 32) * 32];
    ushort* lA1 = &lsA[(w * 32 + 16) * 32];
    ushort* lB0 = &lsB[(w * 32) * 32];
    ushort* lB1 = &lsB[(w * 32 + 16) * 32];

    floatx4 acc[4][4];
    #pragma unroll
    for (int i = 0; i < 4; ++i)
        #pragma unroll
        for (int j = 0; j < 4; ++j)
            acc[i][j] = (floatx4){0.f, 0.f, 0.f, 0.f};

    for (int k0 = 0; k0 < K; k0 += 32) {
        __syncthreads();   // previous iter's fragment reads complete
        async_cp16(gA + k0, lA0);
        async_cp16(gA + (size_t)16 * K + k0, lA1);
        async_cp16(gB + k0, lB0);
        async_cp16(gB + (size_t)16 * K + k0, lB1);
        __syncthreads();   // vmcnt(0) drain + barrier: tiles visible

        short8 af[4], bf[4];
        #pragma unroll
        for (int i = 0; i < 4; ++i) {
            af[i] = *(const short8*)&lsA[(wm + i * 16 + l16) * 32 + ko];
            bf[i] = *(const short8*)&lsB[(wn + i * 16 + l16) * 32 + ko];
        }
        #pragma unroll
        for (int i = 0; i < 4; ++i)
            #pragma unroll
            for (int j = 0; j < 4; ++j)
                acc[i][j] = __builtin_amdgcn_mfma_f32_16x16x32_bf16(
                    af[i], bf[j], acc[i][j], 0, 0, 0);
    }

    // epilogue: C/D layout col=lane&15, row=quad*4+reg
    #pragma unroll
    for (int tn = 0; tn < 4; ++tn) {
        const int n = n0 + wn + tn * 16 + l16;
        const float bv = BIAS ? bias[n] : 0.0f;
        #pragma unroll
        for (int tm = 0; tm < 4; ++tm) {
            const int mbase = m0 + wm + tm * 16 + quad * 4;
            #pragma unroll
            for (int rr = 0; rr < 4; ++rr) {
                float v = acc[tm][tn][rr] + bv;
                if (SILU) v = v / (1.0f + __expf(-v));
                const size_t off = (size_t)(mbase + rr) * N + n;
                if (RESID) v += resid[off];
                if constexpr (OUTF32) ((float*)Cm)[off] = v;
                else                  ((ushort*)Cm)[off] = f2b(v);
            }
        }
    }
}

// ---------------- MFMA flash attention ----------------
// grid (S/64, B*H), block 256 (4 waves). Wave w owns queries [qtile + w*16, +16).
// rs = row stride of Q/K/V (elements); output ctx stride = 1024.
__global__ __launch_bounds__(256) void attn_kernel(
    const ushort* __restrict__ Qm, const ushort* __restrict__ Km,
    const ushort* __restrict__ Vm, const int* __restrict__ amask,
    ushort* __restrict__ Om, int rs)
{
    __shared__ __align__(16) ushort lsQ[64][72];
    __shared__ __align__(16) ushort lsK[64][72];
    __shared__ __align__(16) ushort lsVt[64][72];  // [dim][key]
    __shared__ __align__(16) ushort lsP[64][72];   // wave-private 16-row strips
    __shared__ int lsMk[64];

    const int qt = blockIdx.x;
    const int bh = blockIdx.y;
    const int b = bh >> 4;
    const int h = bh & 15;
    const int t = threadIdx.x;
    const int w = t >> 6;
    const int lane = t & 63;
    const int quad = lane >> 4;
    const int l16 = lane & 15;

    const int q0 = qt * 64;
    const size_t base = ((size_t)b * 2048) * rs + (size_t)h * 64;
    const size_t obase = ((size_t)b * 2048) * 1024 + (size_t)h * 64;

    #pragma unroll
    for (int it = 0; it < 2; ++it) {
        int idx = it * 256 + t;
        int row = idx >> 3;
        int c8 = (idx & 7) << 3;
        *(int4*)&lsQ[row][c8] =
            *(const int4*)(Qm + base + (size_t)(q0 + row) * rs + c8);
    }
    __syncthreads();

    short8 aq0 = *(const short8*)&lsQ[w * 16 + l16][quad * 8];
    short8 aq1 = *(const short8*)&lsQ[w * 16 + l16][32 + quad * 8];

    floatx4 Oacc[4];
    #pragma unroll
    for (int d = 0; d < 4; ++d) Oacc[d] = (floatx4){0.f, 0.f, 0.f, 0.f};
    float m_i[4] = {-INFINITY, -INFINITY, -INFINITY, -INFINITY};
    float l_i[4] = {0.f, 0.f, 0.f, 0.f};

    const int vp = t & 31;
    const int vc8 = (t >> 5) << 3;

    for (int kt = 0; kt <= qt; ++kt) {
        const int k0 = kt * 64;
        __syncthreads();
        #pragma unroll
        for (int it = 0; it < 2; ++it) {
            int idx = it * 256 + t;
            int row = idx >> 3;
            int c8 = (idx & 7) << 3;
            *(int4*)&lsK[row][c8] =
                *(const int4*)(Km + base + (size_t)(k0 + row) * rs + c8);
        }
        {
            int4 v0 = *(const int4*)(Vm + base + (size_t)(k0 + 2 * vp) * rs + vc8);
            int4 v1 = *(const int4*)(Vm + base + (size_t)(k0 + 2 * vp + 1) * rs + vc8);
            const ushort* p0 = (const ushort*)&v0;
            const ushort* p1 = (const ushort*)&v1;
            #pragma unroll
            for (int i = 0; i < 8; ++i) {
                uint pk = (uint)p0[i] | ((uint)p1[i] << 16);
                *(uint*)&lsVt[vc8 + i][2 * vp] = pk;
            }
        }
        if (t < 64) lsMk[t] = amask[b * 2048 + k0 + t];
        __syncthreads();

        floatx4 sa[4];
        #pragma unroll
        for (int j = 0; j < 4; ++j) {
            short8 bk0 = *(const short8*)&lsK[j * 16 + l16][quad * 8];
            short8 bk1 = *(const short8*)&lsK[j * 16 + l16][32 + quad * 8];
            floatx4 z = (floatx4){0.f, 0.f, 0.f, 0.f};
            z = __builtin_amdgcn_mfma_f32_16x16x32_bf16(aq0, bk0, z, 0, 0, 0);
            sa[j] = __builtin_amdgcn_mfma_f32_16x16x32_bf16(aq1, bk1, z, 0, 0, 0);
        }

        const int mj0 = lsMk[l16];
        const int mj1 = lsMk[16 + l16];
        const int mj2 = lsMk[32 + l16];
        const int mj3 = lsMk[48 + l16];
        const bool diag = (kt == qt);

        float alpha[4];
        float pvv[4][4];
        #pragma unroll
        for (int rr = 0; rr < 4; ++rr) {
            const int qrow = w * 16 + quad * 4 + rr;
            float sv[4];
            float mxv = -INFINITY;
            #pragma unroll
            for (int j = 0; j < 4; ++j) {
                const int mjv = (j == 0) ? mj0 : (j == 1) ? mj1 : (j == 2) ? mj2 : mj3;
                float vv = sa[j][rr] * 0.125f;
                const bool valid = (mjv == 1) && (!diag || (j * 16 + l16 <= qrow));
                sv[j] = valid ? vv : -INFINITY;
                mxv = fmaxf(mxv, sv[j]);
            }
            mxv = fmaxf(mxv, __shfl_xor(mxv, 1));
            mxv = fmaxf(mxv, __shfl_xor(mxv, 2));
            mxv = fmaxf(mxv, __shfl_xor(mxv, 4));
            mxv = fmaxf(mxv, __shfl_xor(mxv, 8));
            const float m_new = fmaxf(m_i[rr], mxv);
            const float al = __expf(m_i[rr] - m_new);
            float ps = 0.f;
            #pragma unroll
            for (int j = 0; j < 4; ++j) {
                float p = __expf(sv[j] - m_new);
                pvv[j][rr] = p;
                ps += p;
            }
            ps += __shfl_xor(ps, 1);
            ps += __shfl_xor(ps, 2);
            ps += __shfl_xor(ps, 4);
            ps += __shfl_xor(ps, 8);
            l_i[rr] = l_i[rr] * al + ps;
            m_i[rr] = m_new;
            alpha[rr] = al;
        }

        #pragma unroll
        for (int d = 0; d < 4; ++d)
            #pragma unroll
            for (int rr = 0; rr < 4; ++rr)
                Oacc[d][rr] *= alpha[rr];

        #pragma unroll
        for (int j = 0; j < 4; ++j)
            #pragma unroll
            for (int rr = 0; rr < 4; ++rr)
                lsP[w * 16 + quad * 4 + rr][j * 16 + l16] = f2b(pvv[j][rr]);

        short8 ap0 = *(const short8*)&lsP[w * 16 + l16][quad * 8];
        short8 ap1 = *(const short8*)&lsP[w * 16 + l16][32 + quad * 8];
        #pragma unroll
        for (int d = 0; d < 4; ++d) {
            short8 bv0 = *(const short8*)&lsVt[d * 16 + l16][quad * 8];
            short8 bv1 = *(const short8*)&lsVt[d * 16 + l16][32 + quad * 8];
            Oacc[d] = __builtin_amdgcn_mfma_f32_16x16x32_bf16(ap0, bv0, Oacc[d], 0, 0, 0);
            Oacc[d] = __builtin_amdgcn_mfma_f32_16x16x32_bf16(ap1, bv1, Oacc[d], 0, 0, 0);
        }
    }

    float inv[4];
    #pragma unroll
    for (int rr = 0; rr < 4; ++rr) inv[rr] = 1.0f / l_i[rr];
    #pragma unroll
    for (int rr = 0; rr < 4; ++rr) {
        const int row = q0 + w * 16 + quad * 4 + rr;
        ushort* op = Om + obase + (size_t)row * 1024;
        #pragma unroll
        for (int d = 0; d < 4; ++d)
            op[d * 16 + l16] = f2b(Oacc[d][rr] * inv[rr]);
    }
}

// ---------------- driver ----------------
// ws peak 72 MiB:
//   phase 1: xa [0,16) | qkvb [16,64) | Wqkv_t [64,70) | Wo_t [70,72)
//   phase 2: W1_t [0,8) W2_t [8,16) | yb [16,32) | hb chunk [32,64)
extern "C" void kernel_launch(void* const* d_in, const int* in_sizes, int n_in,
                              void* d_out, int out_size, void* d_ws, size_t ws_size,
                              hipStream_t stream) {
    const float* hidden = (const float*)d_in[0];
    const int*   amask  = (const int*)d_in[1];
    const float* Wq  = (const float*)d_in[2];
    const float* Wk  = (const float*)d_in[3];
    const float* Wv  = (const float*)d_in[4];
    const float* Wo  = (const float*)d_in[5];
    const float* l1g = (const float*)d_in[6];
    const float* l1b = (const float*)d_in[7];
    const float* W1  = (const float*)d_in[8];
    const float* b1  = (const float*)d_in[9];
    const float* W2  = (const float*)d_in[10];
    const float* b2  = (const float*)d_in[11];
    const float* l2g = (const float*)d_in[12];
    const float* l2b = (const float*)d_in[13];

    const int M = 8192;
    const size_t MB = 1048576;
    char* ws = (char*)d_ws;
    ushort* xa    = (ushort*)(ws);            // 16 MB
    ushort* qkvb  = (ushort*)(ws + 16 * MB);  // 48 MB
    ushort* Wqkvt = (ushort*)(ws + 64 * MB);  // 6 MB
    ushort* Wot   = (ushort*)(ws + 70 * MB);  // 2 MB
    ushort* W1t   = (ushort*)(ws);            // 8 MB  (phase 2)
    ushort* W2t   = (ushort*)(ws + 8 * MB);   // 8 MB
    ushort* yb    = (ushort*)(ws + 16 * MB);  // 16 MB
    ushort* hbc   = (ushort*)(ws + 32 * MB);  // 32 MB
    float*  x2    = (float*)d_out;

    // transposed bf16 weights: Wqkv_t rows = [q(1024) | k(1024) | v(1024)], K=1024
    cvt_t_kernel<<<dim3(32, 32), 256, 0, stream>>>(Wq, Wqkvt, 1024, 1024);
    cvt_t_kernel<<<dim3(32, 32), 256, 0, stream>>>(Wk, Wqkvt + (size_t)1024 * 1024, 1024, 1024);
    cvt_t_kernel<<<dim3(32, 32), 256, 0, stream>>>(Wv, Wqkvt + (size_t)2048 * 1024, 1024, 1024);
    cvt_t_kernel<<<dim3(32, 32), 256, 0, stream>>>(Wo, Wot, 1024, 1024);

    ln_kernel<<<M, 256, 0, stream>>>(hidden, l1g, l1b, xa);
    // fused QKV: [M,3072]
    gemm_bt_kernel<false, false, false, false><<<dim3(24, 64), 256, 0, stream>>>(
        xa, Wqkvt, nullptr, nullptr, qkvb, M, 3072, 1024);
    attn_kernel<<<dim3(32, 64), 256, 0, stream>>>(
        qkvb, qkvb + 1024, qkvb + 2048, amask, xa, 3072);
    // x2 = ctx @ Wo + hidden -> fp32 in d_out
    gemm_bt_kernel<false, false, true, true><<<dim3(8, 64), 256, 0, stream>>>(
        xa, Wot, nullptr, hidden, x2, M, 1024, 1024);

    // phase 2 weights into dead xa region
    cvt_t_kernel<<<dim3(128, 32), 256, 0, stream>>>(W1, W1t, 1024, 4096);
    cvt_t_kernel<<<dim3(32, 128), 256, 0, stream>>>(W2, W2t, 4096, 1024);

    ln_kernel<<<M, 256, 0, stream>>>(x2, l2g, l2b, yb);
    // FFN in 2 chunks of 4096 rows; hb chunk (4096x4096 bf16 = 32 MB) in hbc
    for (int mc = 0; mc < 2; ++mc) {
        const size_t off = (size_t)mc * 4096 * 1024;
        gemm_bt_kernel<true, true, false, false><<<dim3(32, 32), 256, 0, stream>>>(
            yb + off, W1t, b1, nullptr, hbc, 4096, 4096, 1024);
        gemm_bt_kernel<true, false, true, true><<<dim3(8, 32), 256, 0, stream>>>(
            hbc, W2t, b2, x2 + off, (void*)(x2 + off), 4096, 1024, 4096);
    }
}

// Round 6
// 724.729 us; speedup vs baseline: 29.2074x; 1.0892x over previous
//
#include <hip/hip_runtime.h>
#include <math.h>

typedef __attribute__((ext_vector_type(8))) short short8;
typedef __attribute__((ext_vector_type(4))) float floatx4;

__device__ __forceinline__ float b2f(ushort u) {
    union { uint i; float f; } c; c.i = ((uint)u) << 16; return c.f;
}
__device__ __forceinline__ ushort f2b(float f) {
    union { float f; uint i; } c; c.f = f;
    return (ushort)((c.i + 0x7fffu + ((c.i >> 16) & 1u)) >> 16);
}

__device__ __forceinline__ void async_cp16(const ushort* g, ushort* l) {
    __builtin_amdgcn_global_load_lds(
        (const __attribute__((address_space(1))) void*)g,
        (__attribute__((address_space(3))) void*)l, 16, 0, 0);
}

// max-reduce over the 16-lane DPP row using full-rate VALU DPP ops
__device__ __forceinline__ float dpp_max16(float x) {
    int y;
    y = __builtin_amdgcn_update_dpp(__float_as_int(x), __float_as_int(x), 0xB1, 0xF, 0xF, false);
    x = fmaxf(x, __int_as_float(y));   // xor 1 (quad_perm 1,0,3,2)
    y = __builtin_amdgcn_update_dpp(__float_as_int(x), __float_as_int(x), 0x4E, 0xF, 0xF, false);
    x = fmaxf(x, __int_as_float(y));   // xor 2 (quad_perm 2,3,0,1)
    y = __builtin_amdgcn_update_dpp(__float_as_int(x), __float_as_int(x), 0x141, 0xF, 0xF, false);
    x = fmaxf(x, __int_as_float(y));   // row_half_mirror: combine quad pairs
    y = __builtin_amdgcn_update_dpp(__float_as_int(x), __float_as_int(x), 0x140, 0xF, 0xF, false);
    x = fmaxf(x, __int_as_float(y));   // row_mirror: combine row halves
    return x;
}

// ---------------- fp32 [K,N] -> bf16 transposed [N,K] ----------------
__global__ __launch_bounds__(256) void cvt_t_kernel(
    const float* __restrict__ S, ushort* __restrict__ D, int K, int N)
{
    __shared__ float ls[32][33];
    const int k0 = blockIdx.y * 32, n0 = blockIdx.x * 32;
    const int t = threadIdx.x;
    const int kr = t >> 3, nc = (t & 7) * 4;
    float4 f = *(const float4*)(S + (size_t)(k0 + kr) * N + n0 + nc);
    ls[kr][nc] = f.x; ls[kr][nc + 1] = f.y; ls[kr][nc + 2] = f.z; ls[kr][nc + 3] = f.w;
    __syncthreads();
    const int nr = t >> 3, kc = (t & 7) * 4;
    ushort4 o;
    o.x = f2b(ls[kc][nr]); o.y = f2b(ls[kc + 1][nr]);
    o.z = f2b(ls[kc + 2][nr]); o.w = f2b(ls[kc + 3][nr]);
    *(ushort4*)(D + (size_t)(n0 + nr) * K + k0 + kc) = o;
}

// ---------------- LayerNorm: fp32 in, bf16 out ----------------
__global__ __launch_bounds__(256) void ln_kernel(
    const float* __restrict__ X, const float* __restrict__ G,
    const float* __restrict__ Bb, ushort* __restrict__ Y)
{
    const int row = blockIdx.x;
    const int t = threadIdx.x;
    const float* xr = X + (size_t)row * 1024;
    float4 p = ((const float4*)xr)[t];
    float s = p.x + p.y + p.z + p.w;
    float s2 = p.x * p.x + p.y * p.y + p.z * p.z + p.w * p.w;
    #pragma unroll
    for (int off = 32; off > 0; off >>= 1) {
        s += __shfl_down(s, off);
        s2 += __shfl_down(s2, off);
    }
    __shared__ float rs1[4], rs2[4];
    if ((t & 63) == 0) { rs1[t >> 6] = s; rs2[t >> 6] = s2; }
    __syncthreads();
    float S1 = rs1[0] + rs1[1] + rs1[2] + rs1[3];
    float S2 = rs2[0] + rs2[1] + rs2[2] + rs2[3];
    float mu = S1 * (1.0f / 1024.0f);
    float var = S2 * (1.0f / 1024.0f) - mu * mu;
    float rstd = rsqrtf(var + 1e-12f);
    float4 gp = ((const float4*)G)[t];
    float4 bp = ((const float4*)Bb)[t];
    ushort4 o;
    o.x = f2b((p.x - mu) * rstd * gp.x + bp.x);
    o.y = f2b((p.y - mu) * rstd * gp.y + bp.y);
    o.z = f2b((p.z - mu) * rstd * gp.z + bp.z);
    o.w = f2b((p.w - mu) * rstd * gp.w + bp.w);
    ((ushort4*)(Y + (size_t)row * 1024))[t] = o;
}

// ---------------- GEMM (B^T form, m97 structure): C[M,N] = A[M,K] @ Bt[N,K]^T
// tile 128 x BN (BN=128 or 64), BK=32, 4 waves, global_load_lds staging.
template<int BN, bool BIAS, bool SILU, bool RESID, bool OUTF32>
__global__ __launch_bounds__(256) void gemm_bt_kernel(
    const ushort* __restrict__ A, const ushort* __restrict__ Bt,
    const float* __restrict__ bias, const float* __restrict__ resid,
    void* __restrict__ Cm, int M, int N, int K)
{
    constexpr int NF = BN / 32;   // n-frags per wave (wave n-tile = BN/2)
    constexpr int BI = BN / 64;   // B staging issues per wave
    __shared__ __align__(16) ushort lsA[128 * 32];
    __shared__ __align__(16) ushort lsB[BN * 32];

    const int t = threadIdx.x;
    const int m0 = blockIdx.y * 128;
    const int n0 = blockIdx.x * BN;
    const int w = t >> 6;
    const int lane = t & 63;
    const int wm = (w >> 1) * 64;
    const int wn = (w & 1) * (BN / 2);
    const int quad = lane >> 4;
    const int l16 = lane & 15;
    const int ko = quad * 8;

    const int lrow = lane >> 2;
    const int scol = (lane & 3) * 8;
    const int srA = w * 32 + lrow;
    const int srB = (BI == 2) ? (w * 32 + lrow) : (w * 16 + lrow);
    const ushort* gA = A + (size_t)(m0 + srA) * K + scol;
    const ushort* gB = Bt + (size_t)(n0 + srB) * K + scol;
    ushort* lA0 = &lsA[(w * 32) * 32];
    ushort* lA1 = &lsA[(w * 32 + 16) * 32];
    ushort* lB0 = (BI == 2) ? &lsB[(w * 32) * 32] : &lsB[(w * 16) * 32];
    ushort* lB1 = (BI == 2) ? &lsB[(w * 32 + 16) * 32] : nullptr;

    floatx4 acc[4][NF];
    #pragma unroll
    for (int i = 0; i < 4; ++i)
        #pragma unroll
        for (int j = 0; j < NF; ++j)
            acc[i][j] = (floatx4){0.f, 0.f, 0.f, 0.f};

    for (int k0 = 0; k0 < K; k0 += 32) {
        __syncthreads();
        async_cp16(gA + k0, lA0);
        async_cp16(gA + (size_t)16 * K + k0, lA1);
        async_cp16(gB + k0, lB0);
        if constexpr (BI == 2) async_cp16(gB + (size_t)16 * K + k0, lB1);
        __syncthreads();

        short8 af[4], bf[NF];
        #pragma unroll
        for (int i = 0; i < 4; ++i)
            af[i] = *(const short8*)&lsA[(wm + i * 16 + l16) * 32 + ko];
        #pragma unroll
        for (int j = 0; j < NF; ++j)
            bf[j] = *(const short8*)&lsB[(wn + j * 16 + l16) * 32 + ko];
        #pragma unroll
        for (int i = 0; i < 4; ++i)
            #pragma unroll
            for (int j = 0; j < NF; ++j)
                acc[i][j] = __builtin_amdgcn_mfma_f32_16x16x32_bf16(
                    af[i], bf[j], acc[i][j], 0, 0, 0);
    }

    #pragma unroll
    for (int tn = 0; tn < NF; ++tn) {
        const int n = n0 + wn + tn * 16 + l16;
        const float bv = BIAS ? bias[n] : 0.0f;
        #pragma unroll
        for (int tm = 0; tm < 4; ++tm) {
            const int mbase = m0 + wm + tm * 16 + quad * 4;
            #pragma unroll
            for (int rr = 0; rr < 4; ++rr) {
                float v = acc[tm][tn][rr] + bv;
                if (SILU) v = v / (1.0f + __expf(-v));
                const size_t off = (size_t)(mbase + rr) * N + n;
                if (RESID) v += resid[off];
                if constexpr (OUTF32) ((float*)Cm)[off] = v;
                else                  ((ushort*)Cm)[off] = f2b(v);
            }
        }
    }
}

// ---------------- MFMA flash attention ----------------
// grid (S/64, B*H), block 256 (4 waves). Wave w owns 16 queries.
// Softmax: row-max via DPP (no LDS shuffles); denominator via ones-MFMA
// (L += P @ 1), rescaled by alpha like O. Heavy q-tiles dispatched first.
__global__ __launch_bounds__(256) void attn_kernel(
    const ushort* __restrict__ Qm, const ushort* __restrict__ Km,
    const ushort* __restrict__ Vm, const int* __restrict__ amask,
    ushort* __restrict__ Om, int rs)
{
    __shared__ __align__(16) ushort lsQ[64][72];
    __shared__ __align__(16) ushort lsK[64][72];
    __shared__ __align__(16) ushort lsVt[64][72];  // [dim][key]
    __shared__ __align__(16) ushort lsP[64][72];   // wave-private strips
    __shared__ int lsMk[64];

    const int qt = gridDim.x - 1 - blockIdx.x;     // heaviest first
    const int bh = blockIdx.y;
    const int b = bh >> 4;
    const int h = bh & 15;
    const int t = threadIdx.x;
    const int w = t >> 6;
    const int lane = t & 63;
    const int quad = lane >> 4;
    const int l16 = lane & 15;

    const int q0 = qt * 64;
    const size_t base = ((size_t)b * 2048) * rs + (size_t)h * 64;
    const size_t obase = ((size_t)b * 2048) * 1024 + (size_t)h * 64;

    #pragma unroll
    for (int it = 0; it < 2; ++it) {
        int idx = it * 256 + t;
        int row = idx >> 3;
        int c8 = (idx & 7) << 3;
        *(int4*)&lsQ[row][c8] =
            *(const int4*)(Qm + base + (size_t)(q0 + row) * rs + c8);
    }
    __syncthreads();

    short8 aq0 = *(const short8*)&lsQ[w * 16 + l16][quad * 8];
    short8 aq1 = *(const short8*)&lsQ[w * 16 + l16][32 + quad * 8];

    short8 ones8;
    #pragma unroll
    for (int i = 0; i < 8; ++i) ones8[i] = (short)0x3F80;  // bf16 1.0

    floatx4 Oacc[4];
    #pragma unroll
    for (int d = 0; d < 4; ++d) Oacc[d] = (floatx4){0.f, 0.f, 0.f, 0.f};
    floatx4 Lacc = (floatx4){0.f, 0.f, 0.f, 0.f};
    float m_i[4] = {-INFINITY, -INFINITY, -INFINITY, -INFINITY};

    const int vp = t & 31;
    const int vc8 = (t >> 5) << 3;

    for (int kt = 0; kt <= qt; ++kt) {
        const int k0 = kt * 64;
        __syncthreads();
        #pragma unroll
        for (int it = 0; it < 2; ++it) {
            int idx = it * 256 + t;
            int row = idx >> 3;
            int c8 = (idx & 7) << 3;
            *(int4*)&lsK[row][c8] =
                *(const int4*)(Km + base + (size_t)(k0 + row) * rs + c8);
        }
        {
            int4 v0 = *(const int4*)(Vm + base + (size_t)(k0 + 2 * vp) * rs + vc8);
            int4 v1 = *(const int4*)(Vm + base + (size_t)(k0 + 2 * vp + 1) * rs + vc8);
            const ushort* p0 = (const ushort*)&v0;
            const ushort* p1 = (const ushort*)&v1;
            #pragma unroll
            for (int i = 0; i < 8; ++i) {
                uint pk = (uint)p0[i] | ((uint)p1[i] << 16);
                *(uint*)&lsVt[vc8 + i][2 * vp] = pk;
            }
        }
        if (t < 64) lsMk[t] = amask[b * 2048 + k0 + t];
        __syncthreads();

        floatx4 sa[4];
        #pragma unroll
        for (int j = 0; j < 4; ++j) {
            short8 bk0 = *(const short8*)&lsK[j * 16 + l16][quad * 8];
            short8 bk1 = *(const short8*)&lsK[j * 16 + l16][32 + quad * 8];
            floatx4 z = (floatx4){0.f, 0.f, 0.f, 0.f};
            z = __builtin_amdgcn_mfma_f32_16x16x32_bf16(aq0, bk0, z, 0, 0, 0);
            sa[j] = __builtin_amdgcn_mfma_f32_16x16x32_bf16(aq1, bk1, z, 0, 0, 0);
        }

        const int mj0 = lsMk[l16];
        const int mj1 = lsMk[16 + l16];
        const int mj2 = lsMk[32 + l16];
        const int mj3 = lsMk[48 + l16];
        const bool diag = (kt == qt);

        float alpha[4];
        float pvv[4][4];
        #pragma unroll
        for (int rr = 0; rr < 4; ++rr) {
            const int qrow = w * 16 + quad * 4 + rr;
            float sv[4];
            float mxv = -INFINITY;
            #pragma unroll
            for (int j = 0; j < 4; ++j) {
                const int mjv = (j == 0) ? mj0 : (j == 1) ? mj1 : (j == 2) ? mj2 : mj3;
                float vv = sa[j][rr] * 0.125f;
                const bool valid = (mjv == 1) && (!diag || (j * 16 + l16 <= qrow));
                sv[j] = valid ? vv : -INFINITY;
                mxv = fmaxf(mxv, sv[j]);
            }
            mxv = dpp_max16(mxv);                       // 16-lane row max, VALU only
            const float m_new = fmaxf(m_i[rr], mxv);
            alpha[rr] = __expf(m_i[rr] - m_new);        // exp(-inf)=0 first tile
            #pragma unroll
            for (int j = 0; j < 4; ++j)
                pvv[j][rr] = __expf(sv[j] - m_new);
            m_i[rr] = m_new;
        }

        #pragma unroll
        for (int rr = 0; rr < 4; ++rr) {
            #pragma unroll
            for (int d = 0; d < 4; ++d) Oacc[d][rr] *= alpha[rr];
            Lacc[rr] *= alpha[rr];
        }

        #pragma unroll
        for (int j = 0; j < 4; ++j)
            #pragma unroll
            for (int rr = 0; rr < 4; ++rr)
                lsP[w * 16 + quad * 4 + rr][j * 16 + l16] = f2b(pvv[j][rr]);

        short8 ap0 = *(const short8*)&lsP[w * 16 + l16][quad * 8];
        short8 ap1 = *(const short8*)&lsP[w * 16 + l16][32 + quad * 8];
        #pragma unroll
        for (int d = 0; d < 4; ++d) {
            short8 bv0 = *(const short8*)&lsVt[d * 16 + l16][quad * 8];
            short8 bv1 = *(const short8*)&lsVt[d * 16 + l16][32 + quad * 8];
            Oacc[d] = __builtin_amdgcn_mfma_f32_16x16x32_bf16(ap0, bv0, Oacc[d], 0, 0, 0);
            Oacc[d] = __builtin_amdgcn_mfma_f32_16x16x32_bf16(ap1, bv1, Oacc[d], 0, 0, 0);
        }
        // softmax denominator: L += P @ ones
        Lacc = __builtin_amdgcn_mfma_f32_16x16x32_bf16(ap0, ones8, Lacc, 0, 0, 0);
        Lacc = __builtin_amdgcn_mfma_f32_16x16x32_bf16(ap1, ones8, Lacc, 0, 0, 0);
    }

    #pragma unroll
    for (int rr = 0; rr < 4; ++rr) {
        const float inv = 1.0f / Lacc[rr];
        const int row = q0 + w * 16 + quad * 4 + rr;
        ushort* op = Om + obase + (size_t)row * 1024;
        #pragma unroll
        for (int d = 0; d < 4; ++d)
            op[d * 16 + l16] = f2b(Oacc[d][rr] * inv);
    }
}

// ---------------- driver ----------------
// ws peak 72 MiB:
//   phase 1: xa [0,16) | qkvb [16,64) | Wqkv_t [64,70) | Wo_t [70,72)
//   phase 2: W1_t [0,8) W2_t [8,16) | yb [16,32) | hb chunk [32,64)
extern "C" void kernel_launch(void* const* d_in, const int* in_sizes, int n_in,
                              void* d_out, int out_size, void* d_ws, size_t ws_size,
                              hipStream_t stream) {
    const float* hidden = (const float*)d_in[0];
    const int*   amask  = (const int*)d_in[1];
    const float* Wq  = (const float*)d_in[2];
    const float* Wk  = (const float*)d_in[3];
    const float* Wv  = (const float*)d_in[4];
    const float* Wo  = (const float*)d_in[5];
    const float* l1g = (const float*)d_in[6];
    const float* l1b = (const float*)d_in[7];
    const float* W1  = (const float*)d_in[8];
    const float* b1  = (const float*)d_in[9];
    const float* W2  = (const float*)d_in[10];
    const float* b2  = (const float*)d_in[11];
    const float* l2g = (const float*)d_in[12];
    const float* l2b = (const float*)d_in[13];

    const int M = 8192;
    const size_t MB = 1048576;
    char* ws = (char*)d_ws;
    ushort* xa    = (ushort*)(ws);
    ushort* qkvb  = (ushort*)(ws + 16 * MB);
    ushort* Wqkvt = (ushort*)(ws + 64 * MB);
    ushort* Wot   = (ushort*)(ws + 70 * MB);
    ushort* W1t   = (ushort*)(ws);
    ushort* W2t   = (ushort*)(ws + 8 * MB);
    ushort* yb    = (ushort*)(ws + 16 * MB);
    ushort* hbc   = (ushort*)(ws + 32 * MB);
    float*  x2    = (float*)d_out;

    cvt_t_kernel<<<dim3(32, 32), 256, 0, stream>>>(Wq, Wqkvt, 1024, 1024);
    cvt_t_kernel<<<dim3(32, 32), 256, 0, stream>>>(Wk, Wqkvt + (size_t)1024 * 1024, 1024, 1024);
    cvt_t_kernel<<<dim3(32, 32), 256, 0, stream>>>(Wv, Wqkvt + (size_t)2048 * 1024, 1024, 1024);
    cvt_t_kernel<<<dim3(32, 32), 256, 0, stream>>>(Wo, Wot, 1024, 1024);

    ln_kernel<<<M, 256, 0, stream>>>(hidden, l1g, l1b, xa);
    gemm_bt_kernel<128, false, false, false, false><<<dim3(24, 64), 256, 0, stream>>>(
        xa, Wqkvt, nullptr, nullptr, qkvb, M, 3072, 1024);
    attn_kernel<<<dim3(32, 64), 256, 0, stream>>>(
        qkvb, qkvb + 1024, qkvb + 2048, amask, xa, 3072);
    gemm_bt_kernel<64, false, false, true, true><<<dim3(16, 64), 256, 0, stream>>>(
        xa, Wot, nullptr, hidden, x2, M, 1024, 1024);

    cvt_t_kernel<<<dim3(128, 32), 256, 0, stream>>>(W1, W1t, 1024, 4096);
    cvt_t_kernel<<<dim3(32, 128), 256, 0, stream>>>(W2, W2t, 4096, 1024);

    ln_kernel<<<M, 256, 0, stream>>>(x2, l2g, l2b, yb);
    for (int mc = 0; mc < 2; ++mc) {
        const size_t off = (size_t)mc * 4096 * 1024;
        gemm_bt_kernel<128, true, true, false, false><<<dim3(32, 32), 256, 0, stream>>>(
            yb + off, W1t, b1, nullptr, hbc, 4096, 4096, 1024);
        gemm_bt_kernel<64, true, false, true, true><<<dim3(16, 32), 256, 0, stream>>>(
            hbc, W2t, b2, x2 + off, (void*)(x2 + off), 4096, 1024, 4096);
    }
}